// Round 1
// baseline (6221.460 us; speedup 1.0000x reference)
//
#include <hip/hip_runtime.h>

static constexpr int NN = 50000;
static constexpr int NE = 800000;

// ---- gcn_norm ----
__global__ void k_init_deg(float* __restrict__ deg) {
  int i = blockIdx.x * 256 + threadIdx.x;
  if (i < NN) deg[i] = 1.0f;  // self-loop weight
}

__global__ void k_deg_scatter(const int* __restrict__ col, const float* __restrict__ w,
                              float* __restrict__ deg) {
  int e = blockIdx.x * 256 + threadIdx.x;
  if (e < NE) atomicAdd(&deg[col[e]], w[e]);
}

__global__ void k_rsqrt(float* __restrict__ d) {
  int i = blockIdx.x * 256 + threadIdx.x;
  if (i < NN) d[i] = rsqrtf(d[i]);  // deg >= 1 always (self-loop)
}

__global__ void k_norm(const int* __restrict__ row, const int* __restrict__ col,
                       const float* __restrict__ w, const float* __restrict__ dinv,
                       float* __restrict__ nrm) {
  int e = blockIdx.x * 256 + threadIdx.x;
  if (e < NE) nrm[e] = dinv[row[e]] * w[e] * dinv[col[e]];
}

// ---- propagate: out = dinv^2 * h (self-loop) then scatter-add edges ----
template<int F>
__global__ void k_selfloop(const float* __restrict__ h, const float* __restrict__ dinv,
                           float* __restrict__ out) {
  constexpr int FQ = F / 4;
  int idx = blockIdx.x * 256 + threadIdx.x;
  if (idx >= NN * FQ) return;
  int node = idx / FQ;
  float di = dinv[node];
  di *= di;
  float4 hv = reinterpret_cast<const float4*>(h)[idx];
  reinterpret_cast<float4*>(out)[idx] = make_float4(di*hv.x, di*hv.y, di*hv.z, di*hv.w);
}

template<int F>
__global__ void k_scatter(const float* __restrict__ h, const int* __restrict__ row,
                          const int* __restrict__ col, const float* __restrict__ nrm,
                          float* __restrict__ out) {
  constexpr int FQ = F / 4;
  int idx = blockIdx.x * 256 + threadIdx.x;
  if (idx >= NE * FQ) return;
  int e  = idx / FQ;
  int fq = idx - e * FQ;
  int r = row[e], c = col[e];
  float nm = nrm[e];
  const float4 hv = *reinterpret_cast<const float4*>(h + (size_t)r * F + fq * 4);
  float* op = out + (size_t)c * F + fq * 4;
  atomicAdd(op + 0, nm * hv.x);
  atomicAdd(op + 1, nm * hv.y);
  atomicAdd(op + 2, nm * hv.z);
  atomicAdd(op + 3, nm * hv.w);
}

// ---- GEMM: C[r, coff:coff+64] (+)= X[r,:K] @ W[K,64] (+ bias) (ReLU opt) ----
template<int K, bool RELU, bool ACC>
__global__ __launch_bounds__(256) void k_gemm(const float* __restrict__ X,
                                              const float* __restrict__ W,
                                              const float* __restrict__ bias,
                                              float* __restrict__ C,
                                              int ldc, int coff) {
  __shared__ float Wl[K * 64];
  int t = threadIdx.x;
  for (int i = t; i < K * 64; i += 256) Wl[i] = W[i];
  __syncthreads();
  int r  = blockIdx.x * 32 + (t >> 3);
  int c0 = (t & 7) * 8;
  if (r >= NN) return;
  const float* xrow = X + (size_t)r * K;
  float acc[8];
#pragma unroll
  for (int j = 0; j < 8; ++j) acc[j] = 0.f;
  for (int k = 0; k < K; k += 4) {
    float4 xq = *reinterpret_cast<const float4*>(xrow + k);
    float xv[4] = {xq.x, xq.y, xq.z, xq.w};
#pragma unroll
    for (int kk = 0; kk < 4; ++kk) {
      float4 wa = *reinterpret_cast<const float4*>(&Wl[(k + kk) * 64 + c0]);
      float4 wb = *reinterpret_cast<const float4*>(&Wl[(k + kk) * 64 + c0 + 4]);
      acc[0] += xv[kk] * wa.x; acc[1] += xv[kk] * wa.y;
      acc[2] += xv[kk] * wa.z; acc[3] += xv[kk] * wa.w;
      acc[4] += xv[kk] * wb.x; acc[5] += xv[kk] * wb.y;
      acc[6] += xv[kk] * wb.z; acc[7] += xv[kk] * wb.w;
    }
  }
  float* crow = C + (size_t)r * ldc + coff + c0;
#pragma unroll
  for (int j = 0; j < 8; ++j) {
    float v = acc[j];
    if (ACC) v += crow[j];
    else     v += bias[c0 + j];
    if (RELU) v = fmaxf(v, 0.f);
    crow[j] = v;
  }
}

// ---- fused conv2+final weights: Wc[p] = W2[p] @ Wl[64p:64p+64,:] ----
__global__ void k_wc(const float* __restrict__ W2, const float* __restrict__ Wlin,
                     float* __restrict__ Wc) {
  int idx = blockIdx.x * 256 + threadIdx.x;  // 3*192*64
  if (idx >= 3 * 192 * 64) return;
  int j = idx & 63;
  int k = (idx >> 6) % 192;
  int p = idx / (192 * 64);
  float s = 0.f;
  for (int m = 0; m < 64; ++m)
    s += W2[(p * 192 + k) * 64 + m] * Wlin[(p * 64 + m) * 64 + j];
  Wc[idx] = s;
}

__global__ void k_bc(const float* __restrict__ b2, const float* __restrict__ Wlin,
                     const float* __restrict__ bl, float* __restrict__ bc) {
  int j = threadIdx.x;  // 64
  float s = bl[j];
  for (int p = 0; p < 3; ++p)
    for (int m = 0; m < 64; ++m)
      s += b2[p * 64 + m] * Wlin[(p * 64 + m) * 64 + j];
  bc[j] = s;
}

extern "C" void kernel_launch(void* const* d_in, const int* in_sizes, int n_in,
                              void* d_out, int out_size, void* d_ws, size_t ws_size,
                              hipStream_t stream) {
  const float* x    = (const float*)d_in[0];
  const int*   ei   = (const int*)d_in[1];
  const float* ew   = (const float*)d_in[2];
  const float* W1   = (const float*)d_in[3];
  const float* b1   = (const float*)d_in[4];
  const float* W2   = (const float*)d_in[5];
  const float* b2   = (const float*)d_in[6];
  const float* Wlin = (const float*)d_in[7];
  const float* bl   = (const float*)d_in[8];
  float* out = (float*)d_out;

  const int* row = ei;
  const int* col = ei + NE;

  float* ws   = (float*)d_ws;
  float* dinv = ws;                      // NN
  float* nrm  = dinv + NN;               // NE
  float* Wc   = nrm + NE;                // 3*192*64
  float* bc   = Wc + 3 * 192 * 64;       // 64
  float* bufA = bc + 64;                 // NN*192  (c1, then q2)
  float* bufB = bufA + (size_t)NN * 192; // NN*192  (p1+p2, then q1)
  float* c1 = bufA;
  float* p1 = bufB;
  float* p2 = bufB + (size_t)NN * 96;
  float* q1 = bufB;
  float* q2 = bufA;

  auto cdiv = [](long long a, long long b) { return (int)((a + b - 1) / b); };

  k_init_deg<<<cdiv(NN, 256), 256, 0, stream>>>(dinv);
  k_deg_scatter<<<cdiv(NE, 256), 256, 0, stream>>>(col, ew, dinv);
  k_rsqrt<<<cdiv(NN, 256), 256, 0, stream>>>(dinv);
  k_norm<<<cdiv(NE, 256), 256, 0, stream>>>(row, col, ew, dinv, nrm);
  k_wc<<<cdiv(3 * 192 * 64, 256), 256, 0, stream>>>(W2, Wlin, Wc);
  k_bc<<<1, 64, 0, stream>>>(b2, Wlin, bl, bc);

  const int GB = cdiv(NN, 32);
  // conv1: c1 = relu([x@W1_0 | (Ax)@W1_1 | (A^2x)@W1_2] + b1)
  k_gemm<96, true, false><<<GB, 256, 0, stream>>>(x, W1, b1, c1, 192, 0);
  k_selfloop<96><<<cdiv(NN * 24, 256), 256, 0, stream>>>(x, dinv, p1);
  k_scatter<96><<<cdiv((long long)NE * 24, 256), 256, 0, stream>>>(x, row, col, nrm, p1);
  k_gemm<96, true, false><<<GB, 256, 0, stream>>>(p1, W1 + 96 * 64, b1 + 64, c1, 192, 64);
  k_selfloop<96><<<cdiv(NN * 24, 256), 256, 0, stream>>>(p1, dinv, p2);
  k_scatter<96><<<cdiv((long long)NE * 24, 256), 256, 0, stream>>>(p1, row, col, nrm, p2);
  k_gemm<96, true, false><<<GB, 256, 0, stream>>>(p2, W1 + 2 * 96 * 64, b1 + 128, c1, 192, 128);

  // fused conv2 + final linear: out = c1@Wc0 + (Ac1)@Wc1 + (A^2c1)@Wc2 + bc
  k_gemm<192, false, false><<<GB, 256, 0, stream>>>(c1, Wc, bc, out, 64, 0);
  k_selfloop<192><<<cdiv(NN * 48, 256), 256, 0, stream>>>(c1, dinv, q1);
  k_scatter<192><<<cdiv((long long)NE * 48, 256), 256, 0, stream>>>(c1, row, col, nrm, q1);
  k_gemm<192, false, true><<<GB, 256, 0, stream>>>(q1, Wc + 192 * 64, nullptr, out, 64, 0);
  k_selfloop<192><<<cdiv(NN * 48, 256), 256, 0, stream>>>(q1, dinv, q2);
  k_scatter<192><<<cdiv((long long)NE * 48, 256), 256, 0, stream>>>(q1, row, col, nrm, q2);
  k_gemm<192, false, true><<<GB, 256, 0, stream>>>(q2, Wc + 2 * 192 * 64, nullptr, out, 64, 0);
}

// Round 2
// 723.090 us; speedup vs baseline: 8.6040x; 8.6040x over previous
//
#include <hip/hip_runtime.h>

static constexpr int NN = 50000;
static constexpr int NE = 800000;

// ---- init: deg=1 (self-loop), cnt=0 ----
__global__ void k_init(float* __restrict__ deg, int* __restrict__ cnt) {
  int i = blockIdx.x * 256 + threadIdx.x;
  if (i < NN) { deg[i] = 1.0f; cnt[i] = 0; }
}

// ---- per-edge: degree accumulate + histogram ----
__global__ void k_deg_hist(const int* __restrict__ col, const float* __restrict__ w,
                           float* __restrict__ deg, int* __restrict__ cnt) {
  int e = blockIdx.x * 256 + threadIdx.x;
  if (e < NE) {
    int c = col[e];
    atomicAdd(&deg[c], w[e]);
    atomicAdd(&cnt[c], 1);
  }
}

__global__ void k_rsqrt(float* __restrict__ d) {
  int i = blockIdx.x * 256 + threadIdx.x;
  if (i < NN) d[i] = rsqrtf(d[i]);  // deg >= 1 always (self-loop)
}

// ---- single-block exclusive scan over cnt[NN] -> rowptr[NN+1], wcur ----
__global__ __launch_bounds__(256) void k_scan(const int* __restrict__ cnt,
                                              int* __restrict__ rowptr,
                                              int* __restrict__ wcur) {
  __shared__ int part[256];
  __shared__ int base[257];
  const int CH = (NN + 255) / 256;
  int t = threadIdx.x;
  int lo = t * CH, hi = min(NN, lo + CH);
  int s = 0;
  for (int i = lo; i < hi; ++i) s += cnt[i];
  part[t] = s;
  __syncthreads();
  if (t == 0) {
    int r = 0;
    for (int i = 0; i < 256; ++i) { base[i] = r; r += part[i]; }
    base[256] = r;
  }
  __syncthreads();
  int r = base[t];
  for (int i = lo; i < hi; ++i) { rowptr[i] = r; wcur[i] = r; r += cnt[i]; }
  if (t == 0) rowptr[NN] = base[256];
}

// ---- fill CSR: srcs/srcnrm sorted by target ----
__global__ void k_fill(const int* __restrict__ row, const int* __restrict__ col,
                       const float* __restrict__ w, const float* __restrict__ dinv,
                       int* __restrict__ wcur, int* __restrict__ srcs,
                       float* __restrict__ srcnrm) {
  int e = blockIdx.x * 256 + threadIdx.x;
  if (e >= NE) return;
  int r = row[e], c = col[e];
  int pos = atomicAdd(&wcur[c], 1);
  srcs[pos] = r;
  srcnrm[pos] = dinv[r] * w[e] * dinv[c];
}

// ---- propagate (gather form, self-loop fused): out[n] = dinv[n]^2*h[n] + sum_e nrm*h[src] ----
template<int F>
__global__ __launch_bounds__(256) void k_gather(const float* __restrict__ h,
                                                const float* __restrict__ dinv,
                                                const int* __restrict__ rowptr,
                                                const int* __restrict__ srcs,
                                                const float* __restrict__ srcnrm,
                                                float* __restrict__ out) {
  constexpr int FQ = F / 4;
  int idx = blockIdx.x * 256 + threadIdx.x;
  if (idx >= NN * FQ) return;
  int node = idx / FQ;
  int fq = idx - node * FQ;
  float di = dinv[node];
  float4 hv = reinterpret_cast<const float4*>(h)[idx];
  float d2 = di * di;
  float4 acc = make_float4(d2 * hv.x, d2 * hv.y, d2 * hv.z, d2 * hv.w);
  int e0 = rowptr[node], e1 = rowptr[node + 1];
  for (int e = e0; e < e1; ++e) {
    int src = srcs[e];
    float nm = srcnrm[e];
    float4 sv = *reinterpret_cast<const float4*>(h + (size_t)src * F + fq * 4);
    acc.x += nm * sv.x; acc.y += nm * sv.y;
    acc.z += nm * sv.z; acc.w += nm * sv.w;
  }
  reinterpret_cast<float4*>(out)[idx] = acc;
}

// ---- GEMM: C[r, coff:coff+64] (+)= X[r,:K] @ W[K,64] (+ bias) (ReLU opt) ----
template<int K, bool RELU, bool ACC>
__global__ __launch_bounds__(256) void k_gemm(const float* __restrict__ X,
                                              const float* __restrict__ W,
                                              const float* __restrict__ bias,
                                              float* __restrict__ C,
                                              int ldc, int coff) {
  __shared__ float Wl[K * 64];
  int t = threadIdx.x;
  for (int i = t; i < K * 64; i += 256) Wl[i] = W[i];
  __syncthreads();
  int r  = blockIdx.x * 32 + (t >> 3);
  int c0 = (t & 7) * 8;
  if (r >= NN) return;
  const float* xrow = X + (size_t)r * K;
  float acc[8];
#pragma unroll
  for (int j = 0; j < 8; ++j) acc[j] = 0.f;
  for (int k = 0; k < K; k += 4) {
    float4 xq = *reinterpret_cast<const float4*>(xrow + k);
    float xv[4] = {xq.x, xq.y, xq.z, xq.w};
#pragma unroll
    for (int kk = 0; kk < 4; ++kk) {
      float4 wa = *reinterpret_cast<const float4*>(&Wl[(k + kk) * 64 + c0]);
      float4 wb = *reinterpret_cast<const float4*>(&Wl[(k + kk) * 64 + c0 + 4]);
      acc[0] += xv[kk] * wa.x; acc[1] += xv[kk] * wa.y;
      acc[2] += xv[kk] * wa.z; acc[3] += xv[kk] * wa.w;
      acc[4] += xv[kk] * wb.x; acc[5] += xv[kk] * wb.y;
      acc[6] += xv[kk] * wb.z; acc[7] += xv[kk] * wb.w;
    }
  }
  float* crow = C + (size_t)r * ldc + coff + c0;
#pragma unroll
  for (int j = 0; j < 8; ++j) {
    float v = acc[j];
    if (ACC) v += crow[j];
    else     v += bias[c0 + j];
    if (RELU) v = fmaxf(v, 0.f);
    crow[j] = v;
  }
}

// ---- fused conv2+final weights: Wc[p] = W2[p] @ Wl[64p:64p+64,:] ----
__global__ void k_wc(const float* __restrict__ W2, const float* __restrict__ Wlin,
                     float* __restrict__ Wc) {
  int idx = blockIdx.x * 256 + threadIdx.x;  // 3*192*64
  if (idx >= 3 * 192 * 64) return;
  int j = idx & 63;
  int k = (idx >> 6) % 192;
  int p = idx / (192 * 64);
  float s = 0.f;
  for (int m = 0; m < 64; ++m)
    s += W2[(p * 192 + k) * 64 + m] * Wlin[(p * 64 + m) * 64 + j];
  Wc[idx] = s;
}

__global__ void k_bc(const float* __restrict__ b2, const float* __restrict__ Wlin,
                     const float* __restrict__ bl, float* __restrict__ bc) {
  int j = threadIdx.x;  // 64
  float s = bl[j];
  for (int p = 0; p < 3; ++p)
    for (int m = 0; m < 64; ++m)
      s += b2[p * 64 + m] * Wlin[(p * 64 + m) * 64 + j];
  bc[j] = s;
}

extern "C" void kernel_launch(void* const* d_in, const int* in_sizes, int n_in,
                              void* d_out, int out_size, void* d_ws, size_t ws_size,
                              hipStream_t stream) {
  const float* x    = (const float*)d_in[0];
  const int*   ei   = (const int*)d_in[1];
  const float* ew   = (const float*)d_in[2];
  const float* W1   = (const float*)d_in[3];
  const float* b1   = (const float*)d_in[4];
  const float* W2   = (const float*)d_in[5];
  const float* b2   = (const float*)d_in[6];
  const float* Wlin = (const float*)d_in[7];
  const float* bl   = (const float*)d_in[8];
  float* out = (float*)d_out;

  const int* row = ei;
  const int* col = ei + NE;

  char* wsb = (char*)d_ws;
  float* dinv   = (float*)wsb;                 wsb += NN * 4;
  int*   cnt    = (int*)wsb;                   wsb += NN * 4;
  int*   rowptr = (int*)wsb;                   wsb += (NN + 1) * 4;
  int*   wcur   = (int*)wsb;                   wsb += NN * 4;
  int*   srcs   = (int*)wsb;                   wsb += NE * 4;
  float* srcnrm = (float*)wsb;                 wsb += NE * 4;
  float* Wc     = (float*)wsb;                 wsb += 3 * 192 * 64 * 4;
  float* bc     = (float*)wsb;                 wsb += 64 * 4;
  // align to 16B
  wsb = (char*)(((size_t)wsb + 15) & ~(size_t)15);
  float* bufA   = (float*)wsb;                 wsb += (size_t)NN * 192 * 4;
  float* bufB   = (float*)wsb;
  float* c1 = bufA;
  float* p1 = bufB;
  float* p2 = bufB + (size_t)NN * 96;
  float* q1 = bufB;
  float* q2 = bufA;

  auto cdiv = [](long long a, long long b) { return (int)((a + b - 1) / b); };

  // gcn_norm + CSR build
  k_init<<<cdiv(NN, 256), 256, 0, stream>>>(dinv, cnt);
  k_deg_hist<<<cdiv(NE, 256), 256, 0, stream>>>(col, ew, dinv, cnt);
  k_rsqrt<<<cdiv(NN, 256), 256, 0, stream>>>(dinv);
  k_scan<<<1, 256, 0, stream>>>(cnt, rowptr, wcur);
  k_fill<<<cdiv(NE, 256), 256, 0, stream>>>(row, col, ew, dinv, wcur, srcs, srcnrm);

  // fused conv2+linear weights
  k_wc<<<cdiv(3 * 192 * 64, 256), 256, 0, stream>>>(W2, Wlin, Wc);
  k_bc<<<1, 64, 0, stream>>>(b2, Wlin, bl, bc);

  const int GB = cdiv(NN, 32);
  // conv1: c1 = relu([x@W1_0 | (Ax)@W1_1 | (A^2x)@W1_2] + b1)
  k_gemm<96, true, false><<<GB, 256, 0, stream>>>(x, W1, b1, c1, 192, 0);
  k_gather<96><<<cdiv(NN * 24, 256), 256, 0, stream>>>(x, dinv, rowptr, srcs, srcnrm, p1);
  k_gemm<96, true, false><<<GB, 256, 0, stream>>>(p1, W1 + 96 * 64, b1 + 64, c1, 192, 64);
  k_gather<96><<<cdiv(NN * 24, 256), 256, 0, stream>>>(p1, dinv, rowptr, srcs, srcnrm, p2);
  k_gemm<96, true, false><<<GB, 256, 0, stream>>>(p2, W1 + 2 * 96 * 64, b1 + 128, c1, 192, 128);

  // fused conv2 + final linear: out = c1@Wc0 + (Ac1)@Wc1 + (A^2c1)@Wc2 + bc
  k_gemm<192, false, false><<<GB, 256, 0, stream>>>(c1, Wc, bc, out, 64, 0);
  k_gather<192><<<cdiv(NN * 48, 256), 256, 0, stream>>>(c1, dinv, rowptr, srcs, srcnrm, q1);
  k_gemm<192, false, true><<<GB, 256, 0, stream>>>(q1, Wc + 192 * 64, nullptr, out, 64, 0);
  k_gather<192><<<cdiv(NN * 48, 256), 256, 0, stream>>>(q1, dinv, rowptr, srcs, srcnrm, q2);
  k_gemm<192, false, true><<<GB, 256, 0, stream>>>(q2, Wc + 2 * 192 * 64, nullptr, out, 64, 0);
}

// Round 3
// 488.652 us; speedup vs baseline: 12.7319x; 1.4798x over previous
//
#include <hip/hip_runtime.h>

static constexpr int NN = 50000;
static constexpr int NE = 800000;
static constexpr int NB = (NN + 255) / 256;  // 196 scan blocks

// ---- init: deg=1 (self-loop), cnt=0 ----
__global__ void k_init(float* __restrict__ deg, int* __restrict__ cnt) {
  int i = blockIdx.x * 256 + threadIdx.x;
  if (i < NN) { deg[i] = 1.0f; cnt[i] = 0; }
}

// ---- per-edge: degree accumulate + histogram ----
__global__ void k_deg_hist(const int* __restrict__ col, const float* __restrict__ w,
                           float* __restrict__ deg, int* __restrict__ cnt) {
  int e = blockIdx.x * 256 + threadIdx.x;
  if (e < NE) {
    int c = col[e];
    atomicAdd(&deg[c], w[e]);
    atomicAdd(&cnt[c], 1);
  }
}

__global__ void k_rsqrt(float* __restrict__ d) {
  int i = blockIdx.x * 256 + threadIdx.x;
  if (i < NN) d[i] = rsqrtf(d[i]);  // deg >= 1 always (self-loop)
}

// ---- hierarchical exclusive scan: cnt[NN] -> rowptr[NN+1], wcur ----
__global__ __launch_bounds__(256) void k_scan_part(const int* __restrict__ cnt,
                                                   int* __restrict__ partial) {
  __shared__ int s[256];
  int t = threadIdx.x;
  int i = blockIdx.x * 256 + t;
  s[t] = (i < NN) ? cnt[i] : 0;
  __syncthreads();
  for (int off = 128; off > 0; off >>= 1) {
    if (t < off) s[t] += s[t + off];
    __syncthreads();
  }
  if (t == 0) partial[blockIdx.x] = s[0];
}

__global__ void k_scan_base(const int* __restrict__ partial, int* __restrict__ base,
                            int* __restrict__ rowptr) {
  __shared__ int s[256];
  int t = threadIdx.x;
  s[t] = (t < NB) ? partial[t] : 0;
  __syncthreads();
  if (t == 0) {
    int run = 0;
    for (int i = 0; i < NB; ++i) { int v = s[i]; s[i] = run; run += v; }
    rowptr[NN] = run;  // == NE
  }
  __syncthreads();
  if (t < NB) base[t] = s[t];
}

__global__ __launch_bounds__(256) void k_scan_final(const int* __restrict__ cnt,
                                                    const int* __restrict__ base,
                                                    int* __restrict__ rowptr,
                                                    int* __restrict__ wcur) {
  __shared__ int s[256];
  int t = threadIdx.x;
  int i = blockIdx.x * 256 + t;
  int v = (i < NN) ? cnt[i] : 0;
  s[t] = v;
  __syncthreads();
#pragma unroll
  for (int off = 1; off < 256; off <<= 1) {
    int a = (t >= off) ? s[t - off] : 0;
    __syncthreads();
    s[t] += a;
    __syncthreads();
  }
  int excl = s[t] - v + base[blockIdx.x];
  if (i < NN) { rowptr[i] = excl; wcur[i] = excl; }
}

// ---- fill CSR: srcs/srcnrm sorted by target ----
__global__ void k_fill(const int* __restrict__ row, const int* __restrict__ col,
                       const float* __restrict__ w, const float* __restrict__ dinv,
                       int* __restrict__ wcur, int* __restrict__ srcs,
                       float* __restrict__ srcnrm) {
  int e = blockIdx.x * 256 + threadIdx.x;
  if (e >= NE) return;
  int r = row[e], c = col[e];
  int pos = atomicAdd(&wcur[c], 1);
  srcs[pos] = r;
  srcnrm[pos] = dinv[r] * w[e] * dinv[c];
}

// ---- propagate (gather, self-loop fused). MODE: 0 plain, 1 out=add+prop, 2 out+=prop ----
template<int F, int MODE>
__global__ __launch_bounds__(256) void k_gather(const float* __restrict__ h,
                                                const float* __restrict__ dinv,
                                                const int* __restrict__ rowptr,
                                                const int* __restrict__ srcs,
                                                const float* __restrict__ srcnrm,
                                                const float* __restrict__ add,
                                                float* __restrict__ out) {
  constexpr int FQ = F / 4;
  int idx = blockIdx.x * 256 + threadIdx.x;
  if (idx >= NN * FQ) return;
  int node = idx / FQ;
  int fq = idx - node * FQ;
  float di = dinv[node];
  float4 hv = reinterpret_cast<const float4*>(h)[idx];
  float d2 = di * di;
  float4 acc = make_float4(d2 * hv.x, d2 * hv.y, d2 * hv.z, d2 * hv.w);
  if (MODE == 1) {
    float4 av = reinterpret_cast<const float4*>(add)[idx];
    acc.x += av.x; acc.y += av.y; acc.z += av.z; acc.w += av.w;
  } else if (MODE == 2) {
    float4 av = reinterpret_cast<const float4*>(out)[idx];
    acc.x += av.x; acc.y += av.y; acc.z += av.z; acc.w += av.w;
  }
  int e0 = rowptr[node], e1 = rowptr[node + 1];
  for (int e = e0; e < e1; ++e) {
    int src = srcs[e];
    float nm = srcnrm[e];
    float4 sv = *reinterpret_cast<const float4*>(h + (size_t)src * F + fq * 4);
    acc.x += nm * sv.x; acc.y += nm * sv.y;
    acc.z += nm * sv.z; acc.w += nm * sv.w;
  }
  reinterpret_cast<float4*>(out)[idx] = acc;
}

// ---- GEMM: C[r, coff:coff+64] (+)= X[r,:K] @ W[K,64] (+ bias) (ReLU opt) ----
template<int K, bool RELU, bool ACC, bool BIAS>
__global__ __launch_bounds__(256) void k_gemm(const float* __restrict__ X,
                                              const float* __restrict__ W,
                                              const float* __restrict__ bias,
                                              float* __restrict__ C,
                                              int ldc, int coff) {
  __shared__ float Wl[K * 64];
  int t = threadIdx.x;
  for (int i = t; i < K * 64; i += 256) Wl[i] = W[i];
  __syncthreads();
  int r  = blockIdx.x * 32 + (t >> 3);
  int c0 = (t & 7) * 8;
  if (r >= NN) return;
  const float* xrow = X + (size_t)r * K;
  float acc[8];
#pragma unroll
  for (int j = 0; j < 8; ++j) acc[j] = 0.f;
  for (int k = 0; k < K; k += 4) {
    float4 xq = *reinterpret_cast<const float4*>(xrow + k);
    float xv[4] = {xq.x, xq.y, xq.z, xq.w};
#pragma unroll
    for (int kk = 0; kk < 4; ++kk) {
      float4 wa = *reinterpret_cast<const float4*>(&Wl[(k + kk) * 64 + c0]);
      float4 wb = *reinterpret_cast<const float4*>(&Wl[(k + kk) * 64 + c0 + 4]);
      acc[0] += xv[kk] * wa.x; acc[1] += xv[kk] * wa.y;
      acc[2] += xv[kk] * wa.z; acc[3] += xv[kk] * wa.w;
      acc[4] += xv[kk] * wb.x; acc[5] += xv[kk] * wb.y;
      acc[6] += xv[kk] * wb.z; acc[7] += xv[kk] * wb.w;
    }
  }
  float* crow = C + (size_t)r * ldc + coff + c0;
#pragma unroll
  for (int j = 0; j < 8; ++j) {
    float v = acc[j];
    if (ACC) v += crow[j];
    if (BIAS) v += bias[c0 + j];
    if (RELU) v = fmaxf(v, 0.f);
    crow[j] = v;
  }
}

// ---- fused conv2+final weights: Wc[p] = W2[p] @ Wl[64p:64p+64,:] ----
__global__ void k_wc(const float* __restrict__ W2, const float* __restrict__ Wlin,
                     float* __restrict__ Wc) {
  int idx = blockIdx.x * 256 + threadIdx.x;  // 3*192*64
  if (idx >= 3 * 192 * 64) return;
  int j = idx & 63;
  int k = (idx >> 6) % 192;
  int p = idx / (192 * 64);
  float s = 0.f;
  for (int m = 0; m < 64; ++m)
    s += W2[(p * 192 + k) * 64 + m] * Wlin[(p * 64 + m) * 64 + j];
  Wc[idx] = s;
}

__global__ void k_bc(const float* __restrict__ b2, const float* __restrict__ Wlin,
                     const float* __restrict__ bl, float* __restrict__ bc) {
  int j = threadIdx.x;  // 64
  float s = bl[j];
  for (int p = 0; p < 3; ++p)
    for (int m = 0; m < 64; ++m)
      s += b2[p * 64 + m] * Wlin[(p * 64 + m) * 64 + j];
  bc[j] = s;
}

extern "C" void kernel_launch(void* const* d_in, const int* in_sizes, int n_in,
                              void* d_out, int out_size, void* d_ws, size_t ws_size,
                              hipStream_t stream) {
  const float* x    = (const float*)d_in[0];
  const int*   ei   = (const int*)d_in[1];
  const float* ew   = (const float*)d_in[2];
  const float* W1   = (const float*)d_in[3];
  const float* b1   = (const float*)d_in[4];
  const float* W2   = (const float*)d_in[5];
  const float* b2   = (const float*)d_in[6];
  const float* Wlin = (const float*)d_in[7];
  const float* bl   = (const float*)d_in[8];
  float* out = (float*)d_out;

  const int* row = ei;
  const int* col = ei + NE;

  char* wsb = (char*)d_ws;
  float* dinv    = (float*)wsb;  wsb += NN * 4;
  int*   cnt     = (int*)wsb;    wsb += NN * 4;
  int*   rowptr  = (int*)wsb;    wsb += (NN + 1) * 4;
  int*   wcur    = (int*)wsb;    wsb += NN * 4;
  int*   partial = (int*)wsb;    wsb += 256 * 4;
  int*   sbase   = (int*)wsb;    wsb += 256 * 4;
  int*   srcs    = (int*)wsb;    wsb += NE * 4;
  float* srcnrm  = (float*)wsb;  wsb += NE * 4;
  float* Wc      = (float*)wsb;  wsb += 3 * 192 * 64 * 4;
  float* bc      = (float*)wsb;  wsb += 64 * 4;
  wsb = (char*)(((size_t)wsb + 15) & ~(size_t)15);
  float* bufA    = (float*)wsb;  wsb += (size_t)NN * 192 * 4;  // c1
  float* bufB    = (float*)wsb;                                 // p1|p2, then z1|z2|s
  float* c1 = bufA;
  float* p1 = bufB;
  float* p2 = bufB + (size_t)NN * 96;
  float* z1 = bufB;
  float* z2 = bufB + (size_t)NN * 64;
  float* sB = bufB + (size_t)NN * 128;

  auto cdiv = [](long long a, long long b) { return (int)((a + b - 1) / b); };

  // gcn_norm + CSR build
  k_init<<<cdiv(NN, 256), 256, 0, stream>>>(dinv, cnt);
  k_deg_hist<<<cdiv(NE, 256), 256, 0, stream>>>(col, ew, dinv, cnt);
  k_rsqrt<<<cdiv(NN, 256), 256, 0, stream>>>(dinv);
  k_scan_part<<<NB, 256, 0, stream>>>(cnt, partial);
  k_scan_base<<<1, 256, 0, stream>>>(partial, sbase, rowptr);
  k_scan_final<<<NB, 256, 0, stream>>>(cnt, sbase, rowptr, wcur);
  k_fill<<<cdiv(NE, 256), 256, 0, stream>>>(row, col, ew, dinv, wcur, srcs, srcnrm);

  // fused conv2+linear weights
  k_wc<<<cdiv(3 * 192 * 64, 256), 256, 0, stream>>>(W2, Wlin, Wc);
  k_bc<<<1, 64, 0, stream>>>(b2, Wlin, bl, bc);

  const int GB = cdiv(NN, 32);
  // conv1: c1 = relu([x@W1_0 | (Ax)@W1_1 | (A^2x)@W1_2] + b1)
  k_gemm<96, true, false, true><<<GB, 256, 0, stream>>>(x, W1, b1, c1, 192, 0);
  k_gather<96, 0><<<cdiv(NN * 24, 256), 256, 0, stream>>>(x, dinv, rowptr, srcs, srcnrm, nullptr, p1);
  k_gemm<96, true, false, true><<<GB, 256, 0, stream>>>(p1, W1 + 96 * 64, b1 + 64, c1, 192, 64);
  k_gather<96, 0><<<cdiv(NN * 24, 256), 256, 0, stream>>>(p1, dinv, rowptr, srcs, srcnrm, nullptr, p2);
  k_gemm<96, true, false, true><<<GB, 256, 0, stream>>>(p2, W1 + 2 * 96 * 64, b1 + 128, c1, 192, 128);

  // conv2 + final linear, re-associated to 64-dim propagation:
  // out = c1@Wc0 + bc + A(z1 + A z2),  z1 = c1@Wc1, z2 = c1@Wc2
  k_gemm<192, false, false, true ><<<GB, 256, 0, stream>>>(c1, Wc,            bc,      out, 64, 0);
  k_gemm<192, false, false, false><<<GB, 256, 0, stream>>>(c1, Wc + 192 * 64, nullptr, z1,  64, 0);
  k_gemm<192, false, false, false><<<GB, 256, 0, stream>>>(c1, Wc + 2 * 192 * 64, nullptr, z2, 64, 0);
  // sB = z1 + A z2
  k_gather<64, 1><<<cdiv(NN * 16, 256), 256, 0, stream>>>(z2, dinv, rowptr, srcs, srcnrm, z1, sB);
  // out += A sB
  k_gather<64, 2><<<cdiv(NN * 16, 256), 256, 0, stream>>>(sB, dinv, rowptr, srcs, srcnrm, nullptr, out);
}

// Round 4
// 441.176 us; speedup vs baseline: 14.1020x; 1.1076x over previous
//
#include <hip/hip_runtime.h>

static constexpr int NN = 50000;
static constexpr int NE = 800000;
static constexpr int NB = (NN + 255) / 256;  // 196 scan blocks
static constexpr float DSCALE = 33554432.f;  // 2^25 fixed-point for degree

// ---- init packed degree/count: deg=1.0 (self-loop), cnt=0 ----
__global__ void k_init(unsigned long long* __restrict__ packed) {
  int i = blockIdx.x * 256 + threadIdx.x;
  if (i < NN) packed[i] = ((unsigned long long)(unsigned)DSCALE) << 32;
}

// ---- per-edge: ONE 64-bit atomic = fixed-point weight (hi) + count (lo) ----
__global__ void k_deg_hist(const int* __restrict__ col, const float* __restrict__ w,
                           unsigned long long* __restrict__ packed) {
  int e = blockIdx.x * 256 + threadIdx.x;
  if (e < NE) {
    unsigned fx = (unsigned)(w[e] * DSCALE + 0.5f);
    atomicAdd(&packed[col[e]], (((unsigned long long)fx) << 32) | 1ull);
  }
}

__global__ void k_dinv(const unsigned long long* __restrict__ packed,
                       float* __restrict__ dinv) {
  int i = blockIdx.x * 256 + threadIdx.x;
  if (i < NN) dinv[i] = rsqrtf((float)(packed[i] >> 32) * (1.0f / DSCALE));
}

// ---- hierarchical exclusive scan over counts (low 32 bits of packed) ----
__global__ __launch_bounds__(256) void k_scan_part(const unsigned long long* __restrict__ packed,
                                                   int* __restrict__ partial) {
  __shared__ int s[256];
  int t = threadIdx.x;
  int i = blockIdx.x * 256 + t;
  s[t] = (i < NN) ? (int)(packed[i] & 0xffffffffu) : 0;
  __syncthreads();
  for (int off = 128; off > 0; off >>= 1) {
    if (t < off) s[t] += s[t + off];
    __syncthreads();
  }
  if (t == 0) partial[blockIdx.x] = s[0];
}

__global__ void k_scan_base(const int* __restrict__ partial, int* __restrict__ base,
                            int* __restrict__ rowptr) {
  __shared__ int s[256];
  int t = threadIdx.x;
  s[t] = (t < NB) ? partial[t] : 0;
  __syncthreads();
  if (t == 0) {
    int run = 0;
    for (int i = 0; i < NB; ++i) { int v = s[i]; s[i] = run; run += v; }
    rowptr[NN] = run;  // == NE
  }
  __syncthreads();
  if (t < NB) base[t] = s[t];
}

__global__ __launch_bounds__(256) void k_scan_final(const unsigned long long* __restrict__ packed,
                                                    const int* __restrict__ base,
                                                    int* __restrict__ rowptr,
                                                    int* __restrict__ wcur) {
  __shared__ int s[256];
  int t = threadIdx.x;
  int i = blockIdx.x * 256 + t;
  int v = (i < NN) ? (int)(packed[i] & 0xffffffffu) : 0;
  s[t] = v;
  __syncthreads();
#pragma unroll
  for (int off = 1; off < 256; off <<= 1) {
    int a = (t >= off) ? s[t - off] : 0;
    __syncthreads();
    s[t] += a;
    __syncthreads();
  }
  int excl = s[t] - v + base[blockIdx.x];
  if (i < NN) { rowptr[i] = excl; wcur[i] = excl; }
}

// ---- fill CSR: packed (src, nrm) records sorted by target ----
__global__ void k_fill(const int* __restrict__ row, const int* __restrict__ col,
                       const float* __restrict__ w, const float* __restrict__ dinv,
                       int* __restrict__ wcur, int2* __restrict__ rec) {
  int e = blockIdx.x * 256 + threadIdx.x;
  if (e >= NE) return;
  int r = row[e], c = col[e];
  int pos = atomicAdd(&wcur[c], 1);
  rec[pos] = make_int2(r, __float_as_int(dinv[r] * w[e] * dinv[c]));
}

// ---- propagate (gather, self-loop fused). MODE: 0 plain, 1 out=add+prop, 2 out+=prop ----
template<int F, int MODE>
__global__ __launch_bounds__(256) void k_gather(const float* __restrict__ h,
                                                const float* __restrict__ dinv,
                                                const int* __restrict__ rowptr,
                                                const int2* __restrict__ rec,
                                                const float* __restrict__ add,
                                                float* __restrict__ out) {
  constexpr int FQ = F / 4;
  int idx = blockIdx.x * 256 + threadIdx.x;
  if (idx >= NN * FQ) return;
  int node = idx / FQ;
  int fq = idx - node * FQ;
  float di = dinv[node];
  float4 hv = reinterpret_cast<const float4*>(h)[idx];
  float d2 = di * di;
  float4 acc = make_float4(d2 * hv.x, d2 * hv.y, d2 * hv.z, d2 * hv.w);
  if (MODE == 1) {
    float4 av = reinterpret_cast<const float4*>(add)[idx];
    acc.x += av.x; acc.y += av.y; acc.z += av.z; acc.w += av.w;
  } else if (MODE == 2) {
    float4 av = reinterpret_cast<const float4*>(out)[idx];
    acc.x += av.x; acc.y += av.y; acc.z += av.z; acc.w += av.w;
  }
  int e0 = rowptr[node], e1 = rowptr[node + 1];
  for (int e = e0; e < e1; ++e) {
    int2 rv = rec[e];
    float nm = __int_as_float(rv.y);
    float4 sv = *reinterpret_cast<const float4*>(h + (size_t)rv.x * F + fq * 4);
    acc.x += nm * sv.x; acc.y += nm * sv.y;
    acc.z += nm * sv.z; acc.w += nm * sv.w;
  }
  reinterpret_cast<float4*>(out)[idx] = acc;
}

// ---- GEMM: C[r, coff:coff+64] (+)= X[r,:K] @ W[K,64], 4 rows/thread ----
template<int K, int ROWS, bool RELU, bool ACC, bool BIAS>
__global__ __launch_bounds__(256) void k_gemm(const float* __restrict__ X,
                                              const float* __restrict__ W,
                                              const float* __restrict__ bias,
                                              float* __restrict__ C,
                                              int ldc, int coff) {
  __shared__ float Wl[K * 64];
  int t = threadIdx.x;
  {
    const float4* Ws = reinterpret_cast<const float4*>(W);
    float4* Wd = reinterpret_cast<float4*>(Wl);
    for (int i = t; i < K * 16; i += 256) Wd[i] = Ws[i];
  }
  __syncthreads();
  int r0 = blockIdx.x * (32 * ROWS) + (t >> 3) * ROWS;
  int c0 = (t & 7) * 8;
  if (r0 >= NN) return;
  int rmax = min(ROWS, NN - r0);
  const float* xp = X + (size_t)r0 * K;
  float acc[ROWS][8];
#pragma unroll
  for (int i = 0; i < ROWS; ++i)
#pragma unroll
    for (int j = 0; j < 8; ++j) acc[i][j] = 0.f;

  for (int k = 0; k < K; k += 4) {
    float4 xq[ROWS];
#pragma unroll
    for (int i = 0; i < ROWS; ++i)
      xq[i] = (i < rmax) ? *reinterpret_cast<const float4*>(xp + (size_t)i * K + k)
                         : make_float4(0.f, 0.f, 0.f, 0.f);
#pragma unroll
    for (int kk = 0; kk < 4; ++kk) {
      float4 wa = *reinterpret_cast<const float4*>(&Wl[(k + kk) * 64 + c0]);
      float4 wb = *reinterpret_cast<const float4*>(&Wl[(k + kk) * 64 + c0 + 4]);
#pragma unroll
      for (int i = 0; i < ROWS; ++i) {
        float xv = (kk == 0) ? xq[i].x : (kk == 1) ? xq[i].y : (kk == 2) ? xq[i].z : xq[i].w;
        acc[i][0] += xv * wa.x; acc[i][1] += xv * wa.y;
        acc[i][2] += xv * wa.z; acc[i][3] += xv * wa.w;
        acc[i][4] += xv * wb.x; acc[i][5] += xv * wb.y;
        acc[i][6] += xv * wb.z; acc[i][7] += xv * wb.w;
      }
    }
  }
#pragma unroll
  for (int i = 0; i < ROWS; ++i) {
    if (i >= rmax) break;
    float* crow = C + (size_t)(r0 + i) * ldc + coff + c0;
    float4 v0 = make_float4(acc[i][0], acc[i][1], acc[i][2], acc[i][3]);
    float4 v1 = make_float4(acc[i][4], acc[i][5], acc[i][6], acc[i][7]);
    if (ACC) {
      float4 o0 = *reinterpret_cast<const float4*>(crow);
      float4 o1 = *reinterpret_cast<const float4*>(crow + 4);
      v0.x += o0.x; v0.y += o0.y; v0.z += o0.z; v0.w += o0.w;
      v1.x += o1.x; v1.y += o1.y; v1.z += o1.z; v1.w += o1.w;
    }
    if (BIAS) {
      float4 b0 = *reinterpret_cast<const float4*>(bias + c0);
      float4 b1 = *reinterpret_cast<const float4*>(bias + c0 + 4);
      v0.x += b0.x; v0.y += b0.y; v0.z += b0.z; v0.w += b0.w;
      v1.x += b1.x; v1.y += b1.y; v1.z += b1.z; v1.w += b1.w;
    }
    if (RELU) {
      v0.x = fmaxf(v0.x, 0.f); v0.y = fmaxf(v0.y, 0.f);
      v0.z = fmaxf(v0.z, 0.f); v0.w = fmaxf(v0.w, 0.f);
      v1.x = fmaxf(v1.x, 0.f); v1.y = fmaxf(v1.y, 0.f);
      v1.z = fmaxf(v1.z, 0.f); v1.w = fmaxf(v1.w, 0.f);
    }
    *reinterpret_cast<float4*>(crow) = v0;
    *reinterpret_cast<float4*>(crow + 4) = v1;
  }
}

// ---- fused conv2+final weights: Wc[p] = W2[p] @ Wl[64p:64p+64,:] ----
__global__ void k_wc(const float* __restrict__ W2, const float* __restrict__ Wlin,
                     float* __restrict__ Wc) {
  int idx = blockIdx.x * 256 + threadIdx.x;  // 3*192*64
  if (idx >= 3 * 192 * 64) return;
  int j = idx & 63;
  int k = (idx >> 6) % 192;
  int p = idx / (192 * 64);
  float s = 0.f;
  for (int m = 0; m < 64; ++m)
    s += W2[(p * 192 + k) * 64 + m] * Wlin[(p * 64 + m) * 64 + j];
  Wc[idx] = s;
}

__global__ void k_bc(const float* __restrict__ b2, const float* __restrict__ Wlin,
                     const float* __restrict__ bl, float* __restrict__ bc) {
  int j = threadIdx.x;  // 64
  float s = bl[j];
  for (int p = 0; p < 3; ++p)
    for (int m = 0; m < 64; ++m)
      s += b2[p * 64 + m] * Wlin[(p * 64 + m) * 64 + j];
  bc[j] = s;
}

extern "C" void kernel_launch(void* const* d_in, const int* in_sizes, int n_in,
                              void* d_out, int out_size, void* d_ws, size_t ws_size,
                              hipStream_t stream) {
  const float* x    = (const float*)d_in[0];
  const int*   ei   = (const int*)d_in[1];
  const float* ew   = (const float*)d_in[2];
  const float* W1   = (const float*)d_in[3];
  const float* b1   = (const float*)d_in[4];
  const float* W2   = (const float*)d_in[5];
  const float* b2   = (const float*)d_in[6];
  const float* Wlin = (const float*)d_in[7];
  const float* bl   = (const float*)d_in[8];
  float* out = (float*)d_out;

  const int* row = ei;
  const int* col = ei + NE;

  char* wsb = (char*)d_ws;
  unsigned long long* packed = (unsigned long long*)wsb; wsb += NN * 8;
  float* dinv    = (float*)wsb;  wsb += NN * 4;
  int*   rowptr  = (int*)wsb;    wsb += (NN + 1) * 4;
  int*   wcur    = (int*)wsb;    wsb += NN * 4;
  int*   partial = (int*)wsb;    wsb += 256 * 4;
  int*   sbase   = (int*)wsb;    wsb += 256 * 4;
  wsb = (char*)(((size_t)wsb + 15) & ~(size_t)15);
  int2*  rec     = (int2*)wsb;   wsb += (size_t)NE * 8;
  float* Wc      = (float*)wsb;  wsb += 3 * 192 * 64 * 4;
  float* bc      = (float*)wsb;  wsb += 64 * 4;
  wsb = (char*)(((size_t)wsb + 15) & ~(size_t)15);
  float* bufA    = (float*)wsb;  wsb += (size_t)NN * 192 * 4;  // c1
  float* bufB    = (float*)wsb;                                 // p1|p2, then z1|z2|sB
  float* c1 = bufA;
  float* p1 = bufB;
  float* p2 = bufB + (size_t)NN * 96;
  float* z1 = bufB;
  float* z2 = bufB + (size_t)NN * 64;
  float* sB = bufB + (size_t)NN * 128;

  auto cdiv = [](long long a, long long b) { return (int)((a + b - 1) / b); };

  // gcn_norm + CSR build
  k_init<<<cdiv(NN, 256), 256, 0, stream>>>(packed);
  k_deg_hist<<<cdiv(NE, 256), 256, 0, stream>>>(col, ew, packed);
  k_dinv<<<cdiv(NN, 256), 256, 0, stream>>>(packed, dinv);
  k_scan_part<<<NB, 256, 0, stream>>>(packed, partial);
  k_scan_base<<<1, 256, 0, stream>>>(partial, sbase, rowptr);
  k_scan_final<<<NB, 256, 0, stream>>>(packed, sbase, rowptr, wcur);
  k_fill<<<cdiv(NE, 256), 256, 0, stream>>>(row, col, ew, dinv, wcur, rec);

  // fused conv2+linear weights
  k_wc<<<cdiv(3 * 192 * 64, 256), 256, 0, stream>>>(W2, Wlin, Wc);
  k_bc<<<1, 64, 0, stream>>>(b2, Wlin, bl, bc);

  const int GB4 = cdiv(NN, 128);
  // conv1: c1 = relu([x@W1_0 | (Ax)@W1_1 | (A^2x)@W1_2] + b1)
  k_gemm<96, 4, true, false, true><<<GB4, 256, 0, stream>>>(x, W1, b1, c1, 192, 0);
  k_gather<96, 0><<<cdiv(NN * 24, 256), 256, 0, stream>>>(x, dinv, rowptr, rec, nullptr, p1);
  k_gemm<96, 4, true, false, true><<<GB4, 256, 0, stream>>>(p1, W1 + 96 * 64, b1 + 64, c1, 192, 64);
  k_gather<96, 0><<<cdiv(NN * 24, 256), 256, 0, stream>>>(p1, dinv, rowptr, rec, nullptr, p2);
  k_gemm<96, 4, true, false, true><<<GB4, 256, 0, stream>>>(p2, W1 + 2 * 96 * 64, b1 + 128, c1, 192, 128);

  // conv2 + final linear, re-associated to 64-dim propagation:
  // out = c1@Wc0 + bc + A(z1 + A z2),  z1 = c1@Wc1, z2 = c1@Wc2
  k_gemm<192, 4, false, false, true ><<<GB4, 256, 0, stream>>>(c1, Wc,                bc,      out, 64, 0);
  k_gemm<192, 4, false, false, false><<<GB4, 256, 0, stream>>>(c1, Wc + 192 * 64,     nullptr, z1,  64, 0);
  k_gemm<192, 4, false, false, false><<<GB4, 256, 0, stream>>>(c1, Wc + 2 * 192 * 64, nullptr, z2,  64, 0);
  // sB = z1 + A z2
  k_gather<64, 1><<<cdiv(NN * 16, 256), 256, 0, stream>>>(z2, dinv, rowptr, rec, z1, sB);
  // out += A sB
  k_gather<64, 2><<<cdiv(NN * 16, 256), 256, 0, stream>>>(sB, dinv, rowptr, rec, nullptr, out);
}

// Round 5
// 329.504 us; speedup vs baseline: 18.8813x; 1.3389x over previous
//
#include <hip/hip_runtime.h>

static constexpr int NN = 50000;
static constexpr int NE = 800000;
static constexpr int NB = (NN + 255) / 256;  // 196 scan blocks
static constexpr float DSCALE = 33554432.f;  // 2^25 fixed-point for degree

typedef __attribute__((ext_vector_type(8))) short bf16x8;
typedef __attribute__((ext_vector_type(4))) float f32x4;

__device__ __forceinline__ unsigned short f2bf(float f) {  // RNE
  unsigned u = __float_as_uint(f);
  u += 0x7fffu + ((u >> 16) & 1u);
  return (unsigned short)(u >> 16);
}
__device__ __forceinline__ float bf_lo(unsigned v) { return __uint_as_float(v << 16); }
__device__ __forceinline__ float bf_hi(unsigned v) { return __uint_as_float(v & 0xffff0000u); }

// ---- init packed degree/count: deg=1.0 (self-loop), cnt=0 ----
__global__ void k_init(unsigned long long* __restrict__ packed) {
  int i = blockIdx.x * 256 + threadIdx.x;
  if (i < NN) packed[i] = ((unsigned long long)(unsigned)DSCALE) << 32;
}

// ---- per-edge: ONE 64-bit atomic = fixed-point weight (hi) + count (lo) ----
__global__ void k_deg_hist(const int* __restrict__ col, const float* __restrict__ w,
                           unsigned long long* __restrict__ packed) {
  int e = blockIdx.x * 256 + threadIdx.x;
  if (e < NE) {
    unsigned fx = (unsigned)(w[e] * DSCALE + 0.5f);
    atomicAdd(&packed[col[e]], (((unsigned long long)fx) << 32) | 1ull);
  }
}

__global__ void k_dinv(const unsigned long long* __restrict__ packed,
                       float* __restrict__ dinv) {
  int i = blockIdx.x * 256 + threadIdx.x;
  if (i < NN) dinv[i] = rsqrtf((float)(packed[i] >> 32) * (1.0f / DSCALE));
}

// ---- hierarchical exclusive scan over counts (low 32 bits of packed) ----
__global__ __launch_bounds__(256) void k_scan_part(const unsigned long long* __restrict__ packed,
                                                   int* __restrict__ partial) {
  __shared__ int s[256];
  int t = threadIdx.x;
  int i = blockIdx.x * 256 + t;
  s[t] = (i < NN) ? (int)(packed[i] & 0xffffffffu) : 0;
  __syncthreads();
  for (int off = 128; off > 0; off >>= 1) {
    if (t < off) s[t] += s[t + off];
    __syncthreads();
  }
  if (t == 0) partial[blockIdx.x] = s[0];
}

__global__ void k_scan_base(const int* __restrict__ partial, int* __restrict__ base,
                            int* __restrict__ rowptr) {
  __shared__ int s[256];
  int t = threadIdx.x;
  s[t] = (t < NB) ? partial[t] : 0;
  __syncthreads();
  if (t == 0) {
    int run = 0;
    for (int i = 0; i < NB; ++i) { int v = s[i]; s[i] = run; run += v; }
    rowptr[NN] = run;  // == NE
  }
  __syncthreads();
  if (t < NB) base[t] = s[t];
}

__global__ __launch_bounds__(256) void k_scan_final(const unsigned long long* __restrict__ packed,
                                                    const int* __restrict__ base,
                                                    int* __restrict__ rowptr,
                                                    int* __restrict__ wcur) {
  __shared__ int s[256];
  int t = threadIdx.x;
  int i = blockIdx.x * 256 + t;
  int v = (i < NN) ? (int)(packed[i] & 0xffffffffu) : 0;
  s[t] = v;
  __syncthreads();
#pragma unroll
  for (int off = 1; off < 256; off <<= 1) {
    int a = (t >= off) ? s[t - off] : 0;
    __syncthreads();
    s[t] += a;
    __syncthreads();
  }
  int excl = s[t] - v + base[blockIdx.x];
  if (i < NN) { rowptr[i] = excl; wcur[i] = excl; }
}

// ---- fill CSR: packed (src, nrm) records sorted by target ----
__global__ void k_fill(const int* __restrict__ row, const int* __restrict__ col,
                       const float* __restrict__ w, const float* __restrict__ dinv,
                       int* __restrict__ wcur, int2* __restrict__ rec) {
  int e = blockIdx.x * 256 + threadIdx.x;
  if (e >= NE) return;
  int r = row[e], c = col[e];
  int pos = atomicAdd(&wcur[c], 1);
  rec[pos] = make_int2(r, __float_as_int(dinv[r] * w[e] * dinv[c]));
}

// ---- cast fp32 -> bf16, 4 at a time ----
__global__ void k_cast(const float* __restrict__ src, unsigned short* __restrict__ dst, int n4) {
  int i = blockIdx.x * 256 + threadIdx.x;
  if (i >= n4) return;
  float4 v = reinterpret_cast<const float4*>(src)[i];
  uint2 o;
  o.x = (unsigned)f2bf(v.x) | ((unsigned)f2bf(v.y) << 16);
  o.y = (unsigned)f2bf(v.z) | ((unsigned)f2bf(v.w) << 16);
  reinterpret_cast<uint2*>(dst)[i] = o;
}

// ---- propagate (bf16 h, fp32 accum). MODE 0: out=prop; 1: out=add+prop; 2: outf+=prop ----
template<int F, int MODE>
__global__ __launch_bounds__(256) void k_gatherb(const unsigned short* __restrict__ h,
                                                 const float* __restrict__ dinv,
                                                 const int* __restrict__ rowptr,
                                                 const int2* __restrict__ rec,
                                                 const unsigned short* __restrict__ add,
                                                 unsigned short* __restrict__ outb,
                                                 float* __restrict__ outf) {
  constexpr int FQ = F / 4;
  int idx = blockIdx.x * 256 + threadIdx.x;
  if (idx >= NN * FQ) return;
  int node = idx / FQ;
  int fq = idx - node * FQ;
  const int off = fq * 4;
  uint2 hv = *reinterpret_cast<const uint2*>(h + (size_t)node * F + off);
  float di = dinv[node];
  float d2 = di * di;
  float a0 = d2 * bf_lo(hv.x), a1 = d2 * bf_hi(hv.x);
  float a2 = d2 * bf_lo(hv.y), a3 = d2 * bf_hi(hv.y);
  if (MODE == 1) {
    uint2 av = *reinterpret_cast<const uint2*>(add + (size_t)node * F + off);
    a0 += bf_lo(av.x); a1 += bf_hi(av.x); a2 += bf_lo(av.y); a3 += bf_hi(av.y);
  } else if (MODE == 2) {
    float4 ov = *reinterpret_cast<const float4*>(outf + (size_t)node * F + off);
    a0 += ov.x; a1 += ov.y; a2 += ov.z; a3 += ov.w;
  }
  int e0 = rowptr[node], e1 = rowptr[node + 1];
  for (int e = e0; e < e1; ++e) {
    int2 rv = rec[e];
    float nm = __int_as_float(rv.y);
    uint2 sv = *reinterpret_cast<const uint2*>(h + (size_t)rv.x * F + off);
    a0 += nm * bf_lo(sv.x); a1 += nm * bf_hi(sv.x);
    a2 += nm * bf_lo(sv.y); a3 += nm * bf_hi(sv.y);
  }
  if (MODE == 2) {
    *reinterpret_cast<float4*>(outf + (size_t)node * F + off) = make_float4(a0, a1, a2, a3);
  } else {
    uint2 o;
    o.x = (unsigned)f2bf(a0) | ((unsigned)f2bf(a1) << 16);
    o.y = (unsigned)f2bf(a2) | ((unsigned)f2bf(a3) << 16);
    *reinterpret_cast<uint2*>(outb + (size_t)node * F + off) = o;
  }
}

// ---- pack weights into MFMA B-lane-fragment order: Bf[kt][nt][lane][8] ----
// B-frag layout (16x16x32): lane holds B[k][col], col=lane&15, k=kt*32+(lane>>4)*8+j
__global__ void k_bfrag(const float* __restrict__ W, unsigned short* __restrict__ Bf,
                        int K, int nmat) {
  int fragc = (K / 32) * 4 * 64;
  int idx = blockIdx.x * 256 + threadIdx.x;
  if (idx >= nmat * fragc) return;
  int mat = idx / fragc;
  int rem = idx - mat * fragc;
  int lane = rem & 63;
  int nt = (rem >> 6) & 3;
  int kt = rem >> 8;
  int lrow = lane & 15, lgrp = lane >> 4;
  const float* Wm = W + (size_t)mat * K * 64;
  unsigned short o[8];
#pragma unroll
  for (int j = 0; j < 8; ++j)
    o[j] = f2bf(Wm[(size_t)(kt * 32 + lgrp * 8 + j) * 64 + nt * 16 + lrow]);
  uint4 pk;
  pk.x = (unsigned)o[0] | ((unsigned)o[1] << 16);
  pk.y = (unsigned)o[2] | ((unsigned)o[3] << 16);
  pk.z = (unsigned)o[4] | ((unsigned)o[5] << 16);
  pk.w = (unsigned)o[6] | ((unsigned)o[7] << 16);
  *reinterpret_cast<uint4*>(Bf + (size_t)idx * 8) = pk;
}

// ---- MFMA GEMM: [NN x K](bf16) @ [K x 64] -> 16-row tile per wave, no LDS ----
// MODE 0: bf16 out, +bias, ReLU; MODE 1: bf16 out; MODE 2: fp32 out, +bias
template<int K, int MODE>
__global__ __launch_bounds__(256) void k_mgemm(const unsigned short* __restrict__ A,
                                               const unsigned short* __restrict__ Bf,
                                               const float* __restrict__ bias,
                                               unsigned short* __restrict__ Cb,
                                               float* __restrict__ Cf,
                                               int ldc, int coff) {
  constexpr int KT = K / 32;
  int lane = threadIdx.x & 63;
  int wave = blockIdx.x * 4 + (threadIdx.x >> 6);
  int r0 = wave * 16;
  if (r0 >= NN) return;
  int lrow = lane & 15, lgrp = lane >> 4;
  const unsigned short* ap = A + (size_t)(r0 + lrow) * K + lgrp * 8;
  f32x4 acc[4];
#pragma unroll
  for (int nt = 0; nt < 4; ++nt) acc[nt] = (f32x4){0.f, 0.f, 0.f, 0.f};
#pragma unroll
  for (int kt = 0; kt < KT; ++kt) {
    bf16x8 af = *reinterpret_cast<const bf16x8*>(ap + kt * 32);
#pragma unroll
    for (int nt = 0; nt < 4; ++nt) {
      bf16x8 bfr = *reinterpret_cast<const bf16x8*>(Bf + (size_t)((kt * 4 + nt) * 64 + lane) * 8);
      acc[nt] = __builtin_amdgcn_mfma_f32_16x16x32_bf16(af, bfr, acc[nt], 0, 0, 0);
    }
  }
#pragma unroll
  for (int nt = 0; nt < 4; ++nt) {
#pragma unroll
    for (int reg = 0; reg < 4; ++reg) {
      int rr = r0 + lgrp * 4 + reg;
      int cc = coff + nt * 16 + lrow;
      float v = acc[nt][reg];
      if (MODE != 1) v += bias[nt * 16 + lrow];
      if (MODE == 0) v = fmaxf(v, 0.f);
      if (MODE == 2) Cf[(size_t)rr * ldc + cc] = v;
      else           Cb[(size_t)rr * ldc + cc] = f2bf(v);
    }
  }
}

// ---- fused conv2+final weights: Wc[p] = W2[p] @ Wl[64p:64p+64,:] (fp32) ----
__global__ void k_wc(const float* __restrict__ W2, const float* __restrict__ Wlin,
                     float* __restrict__ Wc) {
  int idx = blockIdx.x * 256 + threadIdx.x;  // 3*192*64
  if (idx >= 3 * 192 * 64) return;
  int j = idx & 63;
  int k = (idx >> 6) % 192;
  int p = idx / (192 * 64);
  float s = 0.f;
  for (int m = 0; m < 64; ++m)
    s += W2[(p * 192 + k) * 64 + m] * Wlin[(p * 64 + m) * 64 + j];
  Wc[idx] = s;
}

__global__ void k_bc(const float* __restrict__ b2, const float* __restrict__ Wlin,
                     const float* __restrict__ bl, float* __restrict__ bc) {
  int j = threadIdx.x;  // 64
  float s = bl[j];
  for (int p = 0; p < 3; ++p)
    for (int m = 0; m < 64; ++m)
      s += b2[p * 64 + m] * Wlin[(p * 64 + m) * 64 + j];
  bc[j] = s;
}

extern "C" void kernel_launch(void* const* d_in, const int* in_sizes, int n_in,
                              void* d_out, int out_size, void* d_ws, size_t ws_size,
                              hipStream_t stream) {
  const float* x    = (const float*)d_in[0];
  const int*   ei   = (const int*)d_in[1];
  const float* ew   = (const float*)d_in[2];
  const float* W1   = (const float*)d_in[3];
  const float* b1   = (const float*)d_in[4];
  const float* W2   = (const float*)d_in[5];
  const float* b2   = (const float*)d_in[6];
  const float* Wlin = (const float*)d_in[7];
  const float* bl   = (const float*)d_in[8];
  float* out = (float*)d_out;

  const int* row = ei;
  const int* col = ei + NE;

  char* wsb = (char*)d_ws;
  unsigned long long* packed = (unsigned long long*)wsb; wsb += NN * 8;
  float* dinv    = (float*)wsb;  wsb += NN * 4;
  int*   rowptr  = (int*)wsb;    wsb += (NN + 1) * 4;
  int*   wcur    = (int*)wsb;    wsb += NN * 4;
  int*   partial = (int*)wsb;    wsb += 256 * 4;
  int*   sbase   = (int*)wsb;    wsb += 256 * 4;
  wsb = (char*)(((size_t)wsb + 15) & ~(size_t)15);
  int2*  rec     = (int2*)wsb;   wsb += (size_t)NE * 8;
  float* Wc      = (float*)wsb;  wsb += 3 * 192 * 64 * 4;
  float* bc      = (float*)wsb;  wsb += 64 * 4;
  wsb = (char*)(((size_t)wsb + 15) & ~(size_t)15);
  unsigned short* BfW1 = (unsigned short*)wsb; wsb += (size_t)3 * 768 * 8 * 2;   // K=96 frags
  unsigned short* BfWc = (unsigned short*)wsb; wsb += (size_t)3 * 1536 * 8 * 2;  // K=192 frags
  wsb = (char*)(((size_t)wsb + 15) & ~(size_t)15);
  unsigned short* xb   = (unsigned short*)wsb; wsb += (size_t)NN * 96 * 2;
  unsigned short* c1   = (unsigned short*)wsb; wsb += (size_t)NN * 192 * 2;
  unsigned short* bufB = (unsigned short*)wsb;  // p1|p2 (2*96) then z1|z2|sB (3*64)
  unsigned short* p1 = bufB;
  unsigned short* p2 = bufB + (size_t)NN * 96;
  unsigned short* z1 = bufB;
  unsigned short* z2 = bufB + (size_t)NN * 64;
  unsigned short* sB = bufB + (size_t)NN * 128;

  auto cdiv = [](long long a, long long b) { return (int)((a + b - 1) / b); };

  // gcn_norm + CSR build
  k_init<<<cdiv(NN, 256), 256, 0, stream>>>(packed);
  k_deg_hist<<<cdiv(NE, 256), 256, 0, stream>>>(col, ew, packed);
  k_dinv<<<cdiv(NN, 256), 256, 0, stream>>>(packed, dinv);
  k_scan_part<<<NB, 256, 0, stream>>>(packed, partial);
  k_scan_base<<<1, 256, 0, stream>>>(partial, sbase, rowptr);
  k_scan_final<<<NB, 256, 0, stream>>>(packed, sbase, rowptr, wcur);
  k_fill<<<cdiv(NE, 256), 256, 0, stream>>>(row, col, ew, dinv, wcur, rec);

  // weight prep
  k_wc<<<cdiv(3 * 192 * 64, 256), 256, 0, stream>>>(W2, Wlin, Wc);
  k_bc<<<1, 64, 0, stream>>>(b2, Wlin, bl, bc);
  k_bfrag<<<cdiv(3 * 768, 256), 256, 0, stream>>>(W1, BfW1, 96, 3);
  k_bfrag<<<cdiv(3 * 1536, 256), 256, 0, stream>>>(Wc, BfWc, 192, 3);
  k_cast<<<cdiv(NN * 24, 256), 256, 0, stream>>>(x, xb, NN * 24);

  const int GG = cdiv(cdiv(NN, 16), 4);  // 782 blocks, 4 waves each, 16 rows/wave
  // conv1: c1 = relu([x@W1_0 | (Ax)@W1_1 | (A^2x)@W1_2] + b1)   (bf16 activations)
  k_mgemm<96, 0><<<GG, 256, 0, stream>>>(xb, BfW1, b1, c1, nullptr, 192, 0);
  k_gatherb<96, 0><<<cdiv(NN * 24, 256), 256, 0, stream>>>(xb, dinv, rowptr, rec, nullptr, p1, nullptr);
  k_mgemm<96, 0><<<GG, 256, 0, stream>>>(p1, BfW1 + (size_t)768 * 8, b1 + 64, c1, nullptr, 192, 64);
  k_gatherb<96, 0><<<cdiv(NN * 24, 256), 256, 0, stream>>>(p1, dinv, rowptr, rec, nullptr, p2, nullptr);
  k_mgemm<96, 0><<<GG, 256, 0, stream>>>(p2, BfW1 + (size_t)2 * 768 * 8, b1 + 128, c1, nullptr, 192, 128);

  // conv2 + final linear, re-associated to 64-dim propagation:
  // out = c1@Wc0 + bc + A(z1 + A z2),  z1 = c1@Wc1, z2 = c1@Wc2
  k_mgemm<192, 2><<<GG, 256, 0, stream>>>(c1, BfWc, bc, nullptr, out, 64, 0);
  k_mgemm<192, 1><<<GG, 256, 0, stream>>>(c1, BfWc + (size_t)1536 * 8, nullptr, z1, nullptr, 64, 0);
  k_mgemm<192, 1><<<GG, 256, 0, stream>>>(c1, BfWc + (size_t)2 * 1536 * 8, nullptr, z2, nullptr, 64, 0);
  // sB = z1 + A z2
  k_gatherb<64, 1><<<cdiv(NN * 16, 256), 256, 0, stream>>>(z2, dinv, rowptr, rec, z1, sB, nullptr);
  // out += A sB
  k_gatherb<64, 2><<<cdiv(NN * 16, 256), 256, 0, stream>>>(sB, dinv, rowptr, rec, nullptr, nullptr, out);
}